// Round 1
// baseline (11032.111 us; speedup 1.0000x reference)
//
#include <hip/hip_runtime.h>

// FlowRNN (GRU scan with flow-delta residual input), MI355X gfx950.
//
// Design (round 0):
//   - One persistent-ish scan kernel: grid = G(8 batch groups) x S(8 N-slices) = 64 blocks.
//     Each block holds its gate-column slice of all weights as persistent MFMA
//     B-fragments in VGPRs (bf16). Per step: x-part MFMAs pre-spin (independent of
//     recurrence), flag-spin on the group's arrival counter (device-scope), load
//     h/res bf16 fragments directly from ring buffers in ws, 24 rec MFMAs, epilogue
//     (sigmoid/tanh, fp32 h state), publish h/res (write-through atomics) + release add.
//   - residual_output is NOT written by the scan: res[b,t] = out[b,t-1]-out[b,t-2],
//     reconstructed by a final elementwise kernel.
//   - ws usage: 32KB arrival counters (memset 0 per launch) + 2x2x64KB bf16 rings.

typedef __attribute__((ext_vector_type(8))) short bf16x8_t;   // 8 bf16 = 4 VGPRs
typedef __attribute__((ext_vector_type(4))) float f32x4_t;

#define MFMA16(a, b, c) __builtin_amdgcn_mfma_f32_16x16x32_bf16((a), (b), (c), 0, 0, 0)

constexpr int Bb = 128, Tt = 1024, Dd = 512, Hh = 256;
constexpr int Gg = 8;      // batch groups
constexpr int Ss = 8;      // N-slices per group (sync group size)
constexpr int ROWS = Bb / Gg;   // 16 rows per group (MFMA M)
constexpr int Wj = Hh / Ss;     // 32 hidden cols per slice

__device__ __forceinline__ short f2bf(float f) {
  union { float f; unsigned int u; } v; v.f = f;
  unsigned int r = v.u + 0x7fffu + ((v.u >> 16) & 1u);   // RNE
  return (short)(r >> 16);
}

__device__ __forceinline__ bf16x8_t load8_bf(const float* p) {
  const f32x4_t a = *(const f32x4_t*)p;
  const f32x4_t b = *(const f32x4_t*)(p + 4);
  bf16x8_t r;
  r[0] = f2bf(a[0]); r[1] = f2bf(a[1]); r[2] = f2bf(a[2]); r[3] = f2bf(a[3]);
  r[4] = f2bf(b[0]); r[5] = f2bf(b[1]); r[6] = f2bf(b[2]); r[7] = f2bf(b[3]);
  return r;
}

__global__ __launch_bounds__(256, 1)
void flowrnn_scan(const float* __restrict__ x, const float* __restrict__ w_ih,
                  const float* __restrict__ w_hh, const float* __restrict__ b_ih,
                  const float* __restrict__ b_hh, float* __restrict__ out,
                  unsigned int* __restrict__ ws) {
  // LDS
  __shared__ short xstage[ROWS][520];      // bf16 x_t tile, padded stride (16B-aligned rows)
  __shared__ float accS[ROWS][260];        // acc exchange: rz 0-63, nx 64-95, nh 96-127, x 128-255
  __shared__ float hpown[ROWS][Wj];        // fp32 h_prev for this block's own slice
  __shared__ float biasR[Wj], biasZ[Wj], biasNX[Wj], biasNH[Wj];

  const int tid  = threadIdx.x;
  const int wid  = tid >> 6;
  const int lane = tid & 63;
  const int n16  = lane & 15;
  const int q    = lane >> 4;
  const int g    = blockIdx.x >> 3;
  const int s    = blockIdx.x & 7;
  const int j0   = Wj * s;

  unsigned int* arrive = ws;                                      // [Gg][Tt]
  unsigned short* hring = (unsigned short*)(ws + Gg * Tt);        // 2 slots x [Bb][Hh] bf16
  unsigned short* rring = hring + 2 * Bb * Hh;                    // same

  // ---- init: biases, hpown ----
  if (tid < Wj) {
    int j = tid;
    biasR[j]  = b_ih[j0 + j]        + b_hh[j0 + j];
    biasZ[j]  = b_ih[256 + j0 + j]  + b_hh[256 + j0 + j];
    biasNX[j] = b_ih[512 + j0 + j];
    biasNH[j] = b_hh[512 + j0 + j];
  }
  ((float*)hpown)[tid] = 0.f;
  ((float*)hpown)[tid + 256] = 0.f;

  // ---- persistent weight B-fragments (bf16 in VGPRs) ----
  // Recurrent u = [res(0:256), h(256:512)].
  // rz tile (this wave): tile wid: wid<2 -> r-gate cols, else z-gate cols. K=512.
  bf16x8_t brz[16], bn[8], bxp[16], bxs[8];
  {
    int grow = (wid < 2) ? (j0 + wid * 16 + n16) : (256 + j0 + (wid - 2) * 16 + n16);
    for (int c = 0; c < 8; ++c)
      brz[c] = load8_bf(w_ih + (size_t)grow * 768 + c * 32 + q * 8);          // res part
    for (int c = 0; c < 8; ++c)
      brz[8 + c] = load8_bf(w_hh + (size_t)grow * 256 + c * 32 + q * 8);      // h part
  }
  if (wid < 2) {   // n-gate, res operand (waves 0,1)
    int grow = 512 + j0 + wid * 16 + n16;
    for (int c = 0; c < 8; ++c)
      bn[c] = load8_bf(w_ih + (size_t)grow * 768 + c * 32 + q * 8);
  } else {         // n-gate, h operand (waves 2,3)
    int grow = 512 + j0 + (wid - 2) * 16 + n16;
    for (int c = 0; c < 8; ++c)
      bn[c] = load8_bf(w_hh + (size_t)grow * 256 + c * 32 + q * 8);
  }
  // x-part weights (w_ih cols 256:768). 6 N-tiles: xr0,xr1,xz0,xz1,xn0,xn1.
  // wave primary (full K): w0=xr0, w1=xz0, w2=xn0, w3=xn1. secondary (half K):
  // w0=xr1 k0-7, w1=xr1 k8-15, w2=xz1 k0-7, w3=xz1 k8-15.
  {
    int tp = (wid == 3) ? 5 : wid * 2;                 // 0,2,4,5
    int grow = (tp >> 1) * 256 + j0 + (tp & 1) * 16 + n16;
    for (int c = 0; c < 16; ++c)
      bxp[c] = load8_bf(w_ih + (size_t)grow * 768 + 256 + c * 32 + q * 8);
    int ts = (wid < 2) ? 1 : 3;
    int gs = (ts >> 1) * 256 + j0 + (ts & 1) * 16 + n16;
    int cbase = (wid & 1) ? 8 : 0;
    for (int c = 0; c < 8; ++c)
      bxs[c] = load8_bf(w_ih + (size_t)gs * 768 + 256 + (cbase + c) * 32 + q * 8);
  }
  __syncthreads();

  long spin_budget = 30000000;   // deadlock guard: fail fast-ish instead of hanging

  for (int t = 0; t < Tt; ++t) {
    // ---- stage x_t -> LDS bf16 (cooperative, pre-spin) ----
    {
      int row = tid >> 4, seg = tid & 15;
      const float* xp = x + ((size_t)(g * ROWS + row) * Tt + t) * Dd + seg * 32;
      bf16x8_t v0 = load8_bf(xp);
      bf16x8_t v1 = load8_bf(xp + 8);
      bf16x8_t v2 = load8_bf(xp + 16);
      bf16x8_t v3 = load8_bf(xp + 24);
      bf16x8_t* dst = (bf16x8_t*)&xstage[row][seg * 32];
      dst[0] = v0; dst[1] = v1; dst[2] = v2; dst[3] = v3;
    }
    __syncthreads();

    // ---- x-part MFMAs (independent of recurrence) ----
    f32x4_t accP = {0.f, 0.f, 0.f, 0.f}, accSx = {0.f, 0.f, 0.f, 0.f};
    {
      bf16x8_t xa[16];
      for (int c = 0; c < 16; ++c)
        xa[c] = *(const bf16x8_t*)&xstage[n16][c * 32 + q * 8];
      for (int c = 0; c < 16; ++c)
        accP = MFMA16(xa[c], bxp[c], accP);
      int cbase = (wid & 1) ? 8 : 0;
      for (int c = 0; c < 8; ++c)
        accSx = MFMA16(xa[cbase + c], bxs[c], accSx);
    }

    // ---- recurrent part: wait for h_{t-1}, load frags, MFMA ----
    f32x4_t accRZ = {0.f, 0.f, 0.f, 0.f}, accN = {0.f, 0.f, 0.f, 0.f};
    if (t > 0) {
      if (tid == 0) {
        unsigned int* fp = arrive + g * Tt + (t - 1);
        while (__hip_atomic_load(fp, __ATOMIC_RELAXED, __HIP_MEMORY_SCOPE_AGENT) < (unsigned)Ss) {
          __builtin_amdgcn_s_sleep(1);
          if (--spin_budget < 0) break;
        }
        __threadfence();   // acquire: invalidate L1/L2 so ring loads see fresh data
      }
      __syncthreads();
      const int slot = (t - 1) & 1;
      const unsigned short* hb = hring + (size_t)slot * (Bb * Hh);
      const unsigned short* rb = rring + (size_t)slot * (Bb * Hh);
      const int b = g * ROWS + n16;
      bf16x8_t rf[8], hf[8];
      for (int c = 0; c < 8; ++c) {
        rf[c] = *(const bf16x8_t*)(rb + (size_t)b * Hh + c * 32 + q * 8);
        hf[c] = *(const bf16x8_t*)(hb + (size_t)b * Hh + c * 32 + q * 8);
      }
      for (int c = 0; c < 8; ++c) accRZ = MFMA16(rf[c], brz[c], accRZ);
      for (int c = 0; c < 8; ++c) accRZ = MFMA16(hf[c], brz[8 + c], accRZ);
      if (wid < 2) { for (int c = 0; c < 8; ++c) accN = MFMA16(rf[c], bn[c], accN); }
      else         { for (int c = 0; c < 8; ++c) accN = MFMA16(hf[c], bn[c], accN); }
    }

    // ---- dump accumulators to LDS (C/D layout: row=(lane>>4)*4+i, col=lane&15) ----
    {
      const int r0 = q * 4;
      for (int i = 0; i < 4; ++i) accS[r0 + i][wid * 16 + n16] = accRZ[i];
      const int nb = (wid < 2) ? (64 + wid * 16) : (96 + (wid - 2) * 16);
      for (int i = 0; i < 4; ++i) accS[r0 + i][nb + n16] = accN[i];
      const int pc = (wid == 0) ? 128 : (wid == 1) ? 176 : (wid == 2) ? 224 : 240;
      for (int i = 0; i < 4; ++i) accS[r0 + i][pc + n16] = accP[i];
      const int sc = 144 + 16 * wid + ((wid >= 2) ? 16 : 0);   // 144,160,192,208
      for (int i = 0; i < 4; ++i) accS[r0 + i][sc + n16] = accSx[i];
    }
    __syncthreads();

    // ---- epilogue: gates, h update, publish ----
    {
      const int row = tid >> 4;
      const int jp = (tid & 15) * 2;
      float hnew[2], resv[2];
      for (int u = 0; u < 2; ++u) {
        const int j = jp + u;
        float ar  = accS[row][j];
        float az  = accS[row][32 + j];
        float anx = accS[row][64 + j];
        float anh = accS[row][96 + j];
        float xr = (j < 16) ? accS[row][128 + j] : (accS[row][144 + j - 16] + accS[row][160 + j - 16]);
        float xz = (j < 16) ? accS[row][176 + j] : (accS[row][192 + j - 16] + accS[row][208 + j - 16]);
        float xn = (j < 16) ? accS[row][224 + j] : accS[row][240 + j - 16];
        float rg = 1.f / (1.f + __expf(-(ar + xr + biasR[j])));
        float zg = 1.f / (1.f + __expf(-(az + xz + biasZ[j])));
        float narg = (anx + xn + biasNX[j]) + rg * (anh + biasNH[j]);
        float e2 = __expf(2.f * narg);
        float ng = 1.f - 2.f / (e2 + 1.f);          // tanh, saturation-safe
        float hp = hpown[row][j];
        float h  = (1.f - zg) * ng + zg * hp;
        hnew[u] = h; resv[u] = h - hp;
        hpown[row][j] = h;
      }
      const int b = g * ROWS + row;
      float* op = out + ((size_t)b * Tt + t) * Hh + j0 + jp;
      op[0] = hnew[0]; op[1] = hnew[1];
      const int slot = t & 1;
      unsigned int hp32 = ((unsigned int)(unsigned short)f2bf(hnew[0])) |
                          ((unsigned int)(unsigned short)f2bf(hnew[1]) << 16);
      unsigned int rp32 = ((unsigned int)(unsigned short)f2bf(resv[0])) |
                          ((unsigned int)(unsigned short)f2bf(resv[1]) << 16);
      unsigned int* hd = (unsigned int*)(hring + (size_t)slot * (Bb * Hh) + (size_t)b * Hh + j0 + jp);
      unsigned int* rd = (unsigned int*)(rring + (size_t)slot * (Bb * Hh) + (size_t)b * Hh + j0 + jp);
      __hip_atomic_store(hd, hp32, __ATOMIC_RELAXED, __HIP_MEMORY_SCOPE_AGENT);  // write-through
      __hip_atomic_store(rd, rp32, __ATOMIC_RELAXED, __HIP_MEMORY_SCOPE_AGENT);
    }
    __syncthreads();                  // drains each wave's vmcnt before barrier
    if (tid == 0) {
      __threadfence();
      __hip_atomic_fetch_add(arrive + g * Tt + t, 1u, __ATOMIC_RELEASE, __HIP_MEMORY_SCOPE_AGENT);
    }
  }
}

// residual_output[b,t] = out[b,t-1] - out[b,t-2]  (0 for t<1; out[b,0] for t==1)
__global__ void flowrnn_resid(const float* __restrict__ out, float* __restrict__ res) {
  size_t i = (size_t)blockIdx.x * blockDim.x + threadIdx.x;   // over Bb*Tt*(Hh/4) float4s
  const size_t total = (size_t)Bb * Tt * (Hh / 4);
  if (i >= total) return;
  const int j4 = (int)(i & 63);
  const int t  = (int)((i >> 6) & 1023);
  const size_t b = i >> 16;
  const f32x4_t* o = (const f32x4_t*)out;
  const size_t base = b * (size_t)Tt * 64 + j4;
  f32x4_t v = {0.f, 0.f, 0.f, 0.f};
  if (t == 1) v = o[base];
  else if (t >= 2) {
    f32x4_t a = o[base + (size_t)(t - 1) * 64];
    f32x4_t c = o[base + (size_t)(t - 2) * 64];
    v = a - c;
  }
  ((f32x4_t*)res)[base + (size_t)t * 64] = v;
}

extern "C" void kernel_launch(void* const* d_in, const int* in_sizes, int n_in,
                              void* d_out, int out_size, void* d_ws, size_t ws_size,
                              hipStream_t stream) {
  const float* x    = (const float*)d_in[0];
  const float* w_ih = (const float*)d_in[1];
  const float* w_hh = (const float*)d_in[2];
  const float* b_ih = (const float*)d_in[3];
  const float* b_hh = (const float*)d_in[4];
  float* out = (float*)d_out;
  float* res = out + (size_t)Bb * Tt * Hh;

  // zero arrival counters (ws is poisoned 0xAA before every timed launch)
  hipMemsetAsync(d_ws, 0, (size_t)Gg * Tt * sizeof(unsigned int), stream);

  flowrnn_scan<<<Gg * Ss, 256, 0, stream>>>(x, w_ih, w_hh, b_ih, b_hh, out,
                                            (unsigned int*)d_ws);

  const size_t total4 = (size_t)Bb * Tt * (Hh / 4);
  flowrnn_resid<<<(int)((total4 + 255) / 256), 256, 0, stream>>>(out, res);
}

// Round 2
// 10354.581 us; speedup vs baseline: 1.0654x; 1.0654x over previous
//
#include <hip/hip_runtime.h>

// FlowRNN (GRU scan with flow-delta residual), MI355X gfx950 — round 2.
//
// vs round 1 (10.7 ms, MfmaUtil 0.76%, WRITE 4.5 GB):
//  - Removed BOTH __threadfence()s (they lowered to full-L2 buffer_wbl2/buffer_inv
//    per step per block — the 10 us/step stall + 8x write amplification).
//    Cross-block exchange is now entirely cache-bypassing: sc1 write-through
//    atomic stores + sc1 8B atomic loads; release = s_waitcnt(0) before flag add.
//  - Per-wave flag adds (count to 32) + per-wave polling: 3 barriers/step -> 2.
//  - x(t+1) register prefetch issued after barrier1, latency hidden under spin.
//  - residual_output fused into the scan epilogue (resv==ress[t+1]); second
//    kernel deleted.

typedef __attribute__((ext_vector_type(8))) short bf16x8_t;   // 8 bf16 = 4 VGPRs
typedef __attribute__((ext_vector_type(4))) float f32x4_t;

#define MFMA16(a, b, c) __builtin_amdgcn_mfma_f32_16x16x32_bf16((a), (b), (c), 0, 0, 0)

constexpr int Bb = 128, Tt = 1024, Dd = 512, Hh = 256;
constexpr int Gg = 8;            // batch groups
constexpr int Ss = 8;            // N-slice blocks per group
constexpr int ROWS = Bb / Gg;    // 16 rows per group (MFMA M)
constexpr int Wj = Hh / Ss;      // 32 hidden cols per slice
constexpr unsigned FLAG_TARGET = Ss * 4;   // 8 blocks x 4 waves

__device__ __forceinline__ short f2bf(float f) {
  union { float f; unsigned int u; } v; v.f = f;
  unsigned int r = v.u + 0x7fffu + ((v.u >> 16) & 1u);   // RNE
  return (short)(r >> 16);
}

__device__ __forceinline__ bf16x8_t load8_bf(const float* p) {
  const f32x4_t a = *(const f32x4_t*)p;
  const f32x4_t b = *(const f32x4_t*)(p + 4);
  bf16x8_t r;
  r[0] = f2bf(a[0]); r[1] = f2bf(a[1]); r[2] = f2bf(a[2]); r[3] = f2bf(a[3]);
  r[4] = f2bf(b[0]); r[5] = f2bf(b[1]); r[6] = f2bf(b[2]); r[7] = f2bf(b[3]);
  return r;
}

// 16B fragment load that bypasses L1/L2 (two 8B relaxed agent atomic loads -> sc0 sc1)
__device__ __forceinline__ bf16x8_t ringload(const unsigned short* p) {
  unsigned long long lo = __hip_atomic_load((const unsigned long long*)p,
                                            __ATOMIC_RELAXED, __HIP_MEMORY_SCOPE_AGENT);
  unsigned long long hi = __hip_atomic_load((const unsigned long long*)(p + 4),
                                            __ATOMIC_RELAXED, __HIP_MEMORY_SCOPE_AGENT);
  union { unsigned long long u[2]; bf16x8_t v; } r;
  r.u[0] = lo; r.u[1] = hi; return r.v;
}

__global__ __launch_bounds__(256, 1)
void flowrnn_scan(const float* __restrict__ x, const float* __restrict__ w_ih,
                  const float* __restrict__ w_hh, const float* __restrict__ b_ih,
                  const float* __restrict__ b_hh, float* __restrict__ out,
                  unsigned int* __restrict__ ws) {
  __shared__ short xstage[ROWS][520];      // bf16 x_t tile, padded stride
  __shared__ float accS[ROWS][260];        // rz 0-63, nx 64-95, nh 96-127, x 128-255
  __shared__ float hpown[ROWS][Wj];        // fp32 h_prev for this block's own slice
  __shared__ float biasR[Wj], biasZ[Wj], biasNX[Wj], biasNH[Wj];

  const int tid  = threadIdx.x;
  const int wid  = tid >> 6;
  const int lane = tid & 63;
  const int n16  = lane & 15;
  const int q    = lane >> 4;
  const int g    = blockIdx.x >> 3;
  const int s    = blockIdx.x & 7;
  const int j0   = Wj * s;

  unsigned int* arrive = ws;                                      // [Gg][Tt]
  unsigned short* hring = (unsigned short*)(ws + Gg * Tt);        // 2 slots x [Bb][Hh]
  unsigned short* rring = hring + 2 * Bb * Hh;
  float* rout = out + (size_t)Bb * Tt * Hh;                       // residual_output

  if (tid < Wj) {
    int j = tid;
    biasR[j]  = b_ih[j0 + j]        + b_hh[j0 + j];
    biasZ[j]  = b_ih[256 + j0 + j]  + b_hh[256 + j0 + j];
    biasNX[j] = b_ih[512 + j0 + j];
    biasNH[j] = b_hh[512 + j0 + j];
  }
  ((float*)hpown)[tid] = 0.f;
  ((float*)hpown)[tid + 256] = 0.f;

  // ---- persistent weight B-fragments in VGPRs (same layout as round 1) ----
  bf16x8_t brz[16], bn[8], bxp[16], bxs[8];
  {
    int grow = (wid < 2) ? (j0 + wid * 16 + n16) : (256 + j0 + (wid - 2) * 16 + n16);
    for (int c = 0; c < 8; ++c)
      brz[c] = load8_bf(w_ih + (size_t)grow * 768 + c * 32 + q * 8);
    for (int c = 0; c < 8; ++c)
      brz[8 + c] = load8_bf(w_hh + (size_t)grow * 256 + c * 32 + q * 8);
  }
  if (wid < 2) {
    int grow = 512 + j0 + wid * 16 + n16;
    for (int c = 0; c < 8; ++c)
      bn[c] = load8_bf(w_ih + (size_t)grow * 768 + c * 32 + q * 8);
  } else {
    int grow = 512 + j0 + (wid - 2) * 16 + n16;
    for (int c = 0; c < 8; ++c)
      bn[c] = load8_bf(w_hh + (size_t)grow * 256 + c * 32 + q * 8);
  }
  {
    int tp = (wid == 3) ? 5 : wid * 2;
    int grow = (tp >> 1) * 256 + j0 + (tp & 1) * 16 + n16;
    for (int c = 0; c < 16; ++c)
      bxp[c] = load8_bf(w_ih + (size_t)grow * 768 + 256 + c * 32 + q * 8);
    int ts = (wid < 2) ? 1 : 3;
    int gs = (ts >> 1) * 256 + j0 + (ts & 1) * 16 + n16;
    int cbase = (wid & 1) ? 8 : 0;
    for (int c = 0; c < 8; ++c)
      bxs[c] = load8_bf(w_ih + (size_t)gs * 768 + 256 + (cbase + c) * 32 + q * 8);
  }

  // ---- x prefetch (fp32, 8 x f32x4 per thread = one row-segment of x_t) ----
  const int xrow = tid >> 4, xseg = tid & 15;
  const float* xbase = x + (size_t)(g * ROWS + xrow) * Tt * Dd + xseg * 32;
  f32x4_t xpre[8];
  {
    const f32x4_t* xp = (const f32x4_t*)(xbase);   // t = 0
#pragma unroll
    for (int i = 0; i < 8; ++i) xpre[i] = xp[i];
  }
  __syncthreads();

  long spin_budget = 50000000;

  for (int t = 0; t < Tt; ++t) {
    // ---- convert prefetched x(t) -> LDS bf16 ----
    {
      bf16x8_t* dst = (bf16x8_t*)&xstage[xrow][xseg * 32];
#pragma unroll
      for (int i = 0; i < 4; ++i) {
        f32x4_t a = xpre[2 * i], b = xpre[2 * i + 1];
        bf16x8_t v;
        v[0] = f2bf(a[0]); v[1] = f2bf(a[1]); v[2] = f2bf(a[2]); v[3] = f2bf(a[3]);
        v[4] = f2bf(b[0]); v[5] = f2bf(b[1]); v[6] = f2bf(b[2]); v[7] = f2bf(b[3]);
        dst[i] = v;
      }
    }
    __syncthreads();   // barrier1

    // ---- issue x(t+1) prefetch; latency hides under spin, drained at barrier2 ----
    if (t + 1 < Tt) {
      const f32x4_t* xp = (const f32x4_t*)(xbase + (size_t)(t + 1) * Dd);
#pragma unroll
      for (int i = 0; i < 8; ++i) xpre[i] = xp[i];
    }

    // ---- x-part MFMAs ----
    f32x4_t accP = {0.f, 0.f, 0.f, 0.f}, accSx = {0.f, 0.f, 0.f, 0.f};
    {
      bf16x8_t xa[16];
      for (int c = 0; c < 16; ++c)
        xa[c] = *(const bf16x8_t*)&xstage[n16][c * 32 + q * 8];
      for (int c = 0; c < 16; ++c)
        accP = MFMA16(xa[c], bxp[c], accP);
      int cbase = (wid & 1) ? 8 : 0;
      for (int c = 0; c < 8; ++c)
        accSx = MFMA16(xa[cbase + c], bxs[c], accSx);
    }

    // ---- recurrent part: per-wave spin, bypass ring loads, MFMA ----
    f32x4_t accRZ = {0.f, 0.f, 0.f, 0.f}, accN = {0.f, 0.f, 0.f, 0.f};
    if (t > 0) {
      const unsigned int* fp = arrive + g * Tt + (t - 1);
      for (;;) {
        unsigned int v = 0;
        if (lane == 0)
          v = __hip_atomic_load(fp, __ATOMIC_RELAXED, __HIP_MEMORY_SCOPE_AGENT);
        v = (unsigned int)__shfl((int)v, 0, 64);
        if (v >= FLAG_TARGET) break;
        __builtin_amdgcn_s_sleep(1);
        if (--spin_budget < 0) break;
      }
      const int slot = (t - 1) & 1;
      const unsigned short* hb = hring + (size_t)slot * (Bb * Hh);
      const unsigned short* rb = rring + (size_t)slot * (Bb * Hh);
      const int b = g * ROWS + n16;
      bf16x8_t rf[8], hf[8];
      for (int c = 0; c < 8; ++c) {
        rf[c] = ringload(rb + (size_t)b * Hh + c * 32 + q * 8);
        hf[c] = ringload(hb + (size_t)b * Hh + c * 32 + q * 8);
      }
      for (int c = 0; c < 8; ++c) accRZ = MFMA16(rf[c], brz[c], accRZ);
      for (int c = 0; c < 8; ++c) accRZ = MFMA16(hf[c], brz[8 + c], accRZ);
      if (wid < 2) { for (int c = 0; c < 8; ++c) accN = MFMA16(rf[c], bn[c], accN); }
      else         { for (int c = 0; c < 8; ++c) accN = MFMA16(hf[c], bn[c], accN); }
    }

    // ---- dump accumulators to LDS (C/D layout: row=q*4+i, col=n16) ----
    {
      const int r0 = q * 4;
      for (int i = 0; i < 4; ++i) accS[r0 + i][wid * 16 + n16] = accRZ[i];
      const int nb = (wid < 2) ? (64 + wid * 16) : (96 + (wid - 2) * 16);
      for (int i = 0; i < 4; ++i) accS[r0 + i][nb + n16] = accN[i];
      const int pc = (wid == 0) ? 128 : (wid == 1) ? 176 : (wid == 2) ? 224 : 240;
      for (int i = 0; i < 4; ++i) accS[r0 + i][pc + n16] = accP[i];
      const int sc = 144 + 16 * wid + ((wid >= 2) ? 16 : 0);   // 144,160,192,208
      for (int i = 0; i < 4; ++i) accS[r0 + i][sc + n16] = accSx[i];
    }
    __syncthreads();   // barrier2 (also drains xpre prefetch + ring loads)

    // ---- epilogue: gates, h update, publish (earliest first), out/res stores ----
    {
      const int row = tid >> 4;
      const int jp  = (tid & 15) * 2;
      float hnew[2], resv[2];
#pragma unroll
      for (int u = 0; u < 2; ++u) {
        const int j = jp + u;
        float ar  = accS[row][j];
        float az  = accS[row][32 + j];
        float anx = accS[row][64 + j];
        float anh = accS[row][96 + j];
        float xr = (j < 16) ? accS[row][128 + j] : (accS[row][144 + j - 16] + accS[row][160 + j - 16]);
        float xz = (j < 16) ? accS[row][176 + j] : (accS[row][192 + j - 16] + accS[row][208 + j - 16]);
        float xn = (j < 16) ? accS[row][224 + j] : accS[row][240 + j - 16];
        float rg = 1.f / (1.f + __expf(-(ar + xr + biasR[j])));
        float zg = 1.f / (1.f + __expf(-(az + xz + biasZ[j])));
        float narg = (anx + xn + biasNX[j]) + rg * (anh + biasNH[j]);
        float e2 = __expf(2.f * narg);
        float ng = 1.f - 2.f / (e2 + 1.f);          // tanh
        float hp = hpown[row][j];
        float h  = (1.f - zg) * ng + zg * hp;
        hnew[u] = h; resv[u] = h - hp;
      }
      const int b = g * ROWS + row;
      // publish ring first (write-through sc1 stores; drained by s_waitcnt below)
      const int slot = t & 1;
      unsigned int hp32 = ((unsigned int)(unsigned short)f2bf(hnew[0])) |
                          ((unsigned int)(unsigned short)f2bf(hnew[1]) << 16);
      unsigned int rp32 = ((unsigned int)(unsigned short)f2bf(resv[0])) |
                          ((unsigned int)(unsigned short)f2bf(resv[1]) << 16);
      unsigned int* hd = (unsigned int*)(hring + (size_t)slot * (Bb * Hh) + (size_t)b * Hh + j0 + jp);
      unsigned int* rd = (unsigned int*)(rring + (size_t)slot * (Bb * Hh) + (size_t)b * Hh + j0 + jp);
      __hip_atomic_store(hd, hp32, __ATOMIC_RELAXED, __HIP_MEMORY_SCOPE_AGENT);
      __hip_atomic_store(rd, rp32, __ATOMIC_RELAXED, __HIP_MEMORY_SCOPE_AGENT);
      // fp32 outputs (plain cached stores) + own-slice h state
      float* op = out + ((size_t)b * Tt + t) * Hh + j0 + jp;
      op[0] = hnew[0]; op[1] = hnew[1];
      if (t == 0) {
        float* rp0 = rout + ((size_t)b * Tt) * Hh + j0 + jp;
        rp0[0] = 0.f; rp0[1] = 0.f;
      }
      if (t + 1 < Tt) {
        float* rp = rout + ((size_t)b * Tt + t + 1) * Hh + j0 + jp;
        rp[0] = resv[0]; rp[1] = resv[1];
      }
      hpown[row][jp]     = hnew[0];
      hpown[row][jp + 1] = hnew[1];
    }

    // ---- per-wave release: drain own stores to L3, then flag add ----
    __builtin_amdgcn_s_waitcnt(0);
    if (lane == 0)
      __hip_atomic_fetch_add(arrive + g * Tt + t, 1u,
                             __ATOMIC_RELAXED, __HIP_MEMORY_SCOPE_AGENT);
  }
}

extern "C" void kernel_launch(void* const* d_in, const int* in_sizes, int n_in,
                              void* d_out, int out_size, void* d_ws, size_t ws_size,
                              hipStream_t stream) {
  const float* x    = (const float*)d_in[0];
  const float* w_ih = (const float*)d_in[1];
  const float* w_hh = (const float*)d_in[2];
  const float* b_ih = (const float*)d_in[3];
  const float* b_hh = (const float*)d_in[4];
  float* out = (float*)d_out;

  // zero arrival counters (ws is re-poisoned 0xAA before every timed launch)
  hipMemsetAsync(d_ws, 0, (size_t)Gg * Tt * sizeof(unsigned int), stream);

  flowrnn_scan<<<Gg * Ss, 256, 0, stream>>>(x, w_ih, w_hh, b_ih, b_hh, out,
                                            (unsigned int*)d_ws);
}